// Round 7
// baseline (391.220 us; speedup 1.0000x reference)
//
#include <hip/hip_runtime.h>

#define K_ITERS 50

typedef float v4f __attribute__((ext_vector_type(4)));

// LDS float layout:
//  [0, 4624)      : setup scratch (h_w 2700 | r_w 1350 | h_b 150) -> X0 (68x68 ring-2) -> vA (66x68 ring-1)
//  [4624, 9248)   : X1 (68x68 ring-2)  -> reused as vB (66x68 ring-1)
//  [9248, 13736)  : R  (66x68 ring-1)  -- intact through phase 5
//  [13736, 14178) : weights: w2(162) rhb(+162) qw(+171,180) qb(+351,10) fcw(+361,80) rb(+441)
//  [14180, 14300) : QW4: v-half of q_w as float4-aligned rows qw4[c][ky] = {w0,w1,w2,pad}
#define SR_OFF 9248
#define SW_OFF 13736
#define QW4_OFF 14180
#define LDS_TOT 14300

// VI step. The register allocator is hard-capped at 128 VGPRs (measured
// VGPR_Count=124 = qr80+nb36+vmax8 across every variant; launch-bounds, asm
// pins, readfirstlane and global/SMEM routing all failed to move it), so the
// 90 loop weights MUST be reloaded from LDS every step. The binding pipe is
// LDS *instruction issue*: 90 uniform ds_read_b32 x 8 waves ~= 4200 cyc/CU/step
// on top of ~1100 cyc tile traffic > ~3160 cyc VALU floor. Fix: reload each
// channel's 9 weights as 3 uniform ds_read_b128 from a float4-aligned copy
// (volatile ext-vector load: compiler cannot split it into b32s, cannot hoist
// it into spilling live ranges, cannot remat it differently). 30 instrs/wave
// instead of 90 -> LDS ~2500 cyc < VALU floor -> VALU-bound loop.
__device__ __forceinline__ void vi_step(const float* __restrict__ cur, float* __restrict__ nxt,
                                        int row, int col0,
                                        const float (&qr)[10][8], const float* __restrict__ qw4) {
    float nb[3][12];
#pragma unroll
    for (int dy = 0; dy < 3; ++dy) {
#pragma unroll
        for (int j = 0; j < 3; ++j) {
            float4 v = *(const float4*)&cur[(row + dy) * 68 + col0 + 4 * j];
            nb[dy][4 * j + 0] = v.x; nb[dy][4 * j + 1] = v.y;
            nb[dy][4 * j + 2] = v.z; nb[dy][4 * j + 3] = v.w;
        }
    }
    float vmax[8];
#pragma unroll
    for (int c = 0; c < 10; ++c) {
        const volatile v4f* wq = (const volatile v4f*)(qw4 + 12 * c);
        v4f w0 = wq[0];   // ky=0: {w[0],w[1],w[2],pad}
        v4f w1 = wq[1];   // ky=1
        v4f w2 = wq[2];   // ky=2
#pragma unroll
        for (int p = 0; p < 8; ++p) {
            float acc = qr[c][p];
            // same ky-major / kx-minor fmaf order as always -> bitwise identical
            acc = fmaf(w0.x, nb[0][p + 0], acc);
            acc = fmaf(w0.y, nb[0][p + 1], acc);
            acc = fmaf(w0.z, nb[0][p + 2], acc);
            acc = fmaf(w1.x, nb[1][p + 0], acc);
            acc = fmaf(w1.y, nb[1][p + 1], acc);
            acc = fmaf(w1.z, nb[1][p + 2], acc);
            acc = fmaf(w2.x, nb[2][p + 0], acc);
            acc = fmaf(w2.y, nb[2][p + 1], acc);
            acc = fmaf(w2.z, nb[2][p + 2], acc);
            vmax[p] = (c == 0) ? acc : fmaxf(vmax[p], acc);
        }
    }
#pragma unroll
    for (int p = 0; p < 8; ++p)
        nxt[(row + 1) * 68 + col0 + 1 + p] = vmax[p];
}

// (512,2): best-measured config (124-125us; (512,1) regressed to ~160us).
// qr indexed ONLY with compile-time constants (a runtime index demotes the
// whole array to scratch: that was the 20.5 MB WRITE_SIZE regression).
__launch_bounds__(512, 2)
__global__ void vin_main(const float* __restrict__ x,
                         const int* __restrict__ pos_x, const int* __restrict__ pos_y,
                         const float* __restrict__ h_w, const float* __restrict__ h_b,
                         const float* __restrict__ r_w, const float* __restrict__ r_b,
                         const float* __restrict__ q_w, const float* __restrict__ q_b,
                         const float* __restrict__ fc_w, float* __restrict__ out) {
    __shared__ __align__(16) float S[LDS_TOT];
    const int tid = threadIdx.x;
    const int b = blockIdx.x;
    const int row = tid >> 3;          // 0..63
    const int col0 = (tid & 7) << 3;   // 0,8,..,56
    float* SW = S + SW_OFF;

    // phase A: stage raw weights into scratch (region later zeroed for X0/X1),
    //          and loop weights into SW[171..442)
    for (int i = tid; i < 2700; i += 512) S[i] = h_w[i];
    for (int i = tid; i < 1350; i += 512) S[2700 + i] = r_w[i];
    if (tid < 150) S[4050 + tid] = h_b[tid];
    for (int i = tid; i < 180; i += 512) SW[171 + i] = q_w[i];
    if (tid < 10) SW[351 + tid] = q_b[tid];
    for (int i = tid; i < 80; i += 512) SW[361 + i] = fc_w[i];
    if (tid == 0) SW[441] = r_b[0];
    __syncthreads();

    // phase B: composite 2-stage conv weights w2[2][9][9] + rhb[9] (fmaf order
    // identical to the original vin_setup kernel -> bitwise-identical results)
    if (tid < 162) {
        int i = tid / 81, rem = tid % 81, dq = rem / 9, ds = rem % 9;
        const float* rw = S + 2700;
        float s = 0.f;
        for (int m = 0; m < 150; ++m)
            s = fmaf(rw[m * 9 + dq], S[(m * 2 + i) * 9 + ds], s);
        SW[tid] = s;
    } else if (tid < 171) {
        int dq = tid - 162;
        const float* rw = S + 2700;
        const float* hb = S + 4050;
        float s = 0.f;
        for (int m = 0; m < 150; ++m)
            s = fmaf(rw[m * 9 + dq], hb[m], s);
        SW[tid] = s;
    }
    __syncthreads();

    // phase 0: zero X0/X1/R regions (13736 = 4*3434 floats)
    float4 z4 = make_float4(0.f, 0.f, 0.f, 0.f);
    for (int i = tid; i < 3434; i += 512) ((float4*)S)[i] = z4;
    __syncthreads();

    // phase 1: stage x[b] into X0/X1 interior (ring-2 stays zero)
    {
        const float4* xg = (const float4*)(x + (size_t)b * 8192);
        for (int i = tid; i < 2048; i += 512) {
            float4 v = xg[i];
            int ch = i >> 10, rem = i & 1023;
            int y = rem >> 4, xc = (rem & 15) << 2;
            float* dst = S + ch * 4624 + (y + 2) * 68 + xc + 2;
            dst[0] = v.x; dst[1] = v.y; dst[2] = v.z; dst[3] = v.w;
        }
    }
    __syncthreads();

    // phase 2: r = composite 2-stage conv via w2/rhb, exact border clipping on q
    {
        float xb0[5][12], xb1[5][12];
        const float* X0 = S;
        const float* X1 = S + 4624;
#pragma unroll
        for (int dy = 0; dy < 5; ++dy) {
#pragma unroll
            for (int j = 0; j < 3; ++j) {
                float4 a = *(const float4*)&X0[(row + dy) * 68 + col0 + 4 * j];
                xb0[dy][4 * j + 0] = a.x; xb0[dy][4 * j + 1] = a.y;
                xb0[dy][4 * j + 2] = a.z; xb0[dy][4 * j + 3] = a.w;
                float4 c = *(const float4*)&X1[(row + dy) * 68 + col0 + 4 * j];
                xb1[dy][4 * j + 0] = c.x; xb1[dy][4 * j + 1] = c.y;
                xb1[dy][4 * j + 2] = c.z; xb1[dy][4 * j + 3] = c.w;
            }
        }
        float racc[8];
        float rbv = SW[441];
#pragma unroll
        for (int p = 0; p < 8; ++p) racc[p] = rbv;
#pragma unroll
        for (int dqy = 0; dqy < 3; ++dqy) {
            bool rowok = (row + dqy >= 1) && (row + dqy <= 64);
#pragma unroll
            for (int dqx = 0; dqx < 3; ++dqx) {
                int dq = dqy * 3 + dqx;
                float rh = SW[162 + dq];
                float w20[9], w21[9];
#pragma unroll
                for (int ds = 0; ds < 9; ++ds) {
                    w20[ds] = SW[dq * 9 + ds];
                    w21[ds] = SW[81 + dq * 9 + ds];
                }
#pragma unroll
                for (int p = 0; p < 8; ++p) {
                    float t = rh;
#pragma unroll
                    for (int dsy = 0; dsy < 3; ++dsy)
#pragma unroll
                        for (int dsx = 0; dsx < 3; ++dsx) {
                            int ds = dsy * 3 + dsx;
                            t = fmaf(w20[ds], xb0[dqy + dsy][p + dqx + dsx], t);
                            t = fmaf(w21[ds], xb1[dqy + dsy][p + dqx + dsx], t);
                        }
                    int qx = col0 + p + dqx - 1;
                    bool ok = rowok && (qx >= 0) && (qx < 64);
                    racc[p] += ok ? t : 0.f;
                }
            }
        }
        float* SR = S + SR_OFF;
#pragma unroll
        for (int p = 0; p < 8; ++p)
            SR[(row + 1) * 68 + col0 + 1 + p] = racc[p];
    }
    __syncthreads();

    // phase 3: qr = conv(r, q_w[:,0]) + q_b into registers; build QW4; re-zero v buffers
    float qr[10][8];
    {
        float rnb[3][12];
        const float* SR = S + SR_OFF;
#pragma unroll
        for (int dy = 0; dy < 3; ++dy) {
#pragma unroll
            for (int j = 0; j < 3; ++j) {
                float4 v = *(const float4*)&SR[(row + dy) * 68 + col0 + 4 * j];
                rnb[dy][4 * j + 0] = v.x; rnb[dy][4 * j + 1] = v.y;
                rnb[dy][4 * j + 2] = v.z; rnb[dy][4 * j + 3] = v.w;
            }
        }
#pragma unroll
        for (int c = 0; c < 10; ++c) {
            float qbc = SW[351 + c];
            float w[9];
#pragma unroll
            for (int j = 0; j < 9; ++j) w[j] = SW[171 + c * 18 + j];
#pragma unroll
            for (int p = 0; p < 8; ++p) {
                float acc = qbc;
#pragma unroll
                for (int ky = 0; ky < 3; ++ky)
#pragma unroll
                    for (int kx = 0; kx < 3; ++kx)
                        acc = fmaf(w[ky * 3 + kx], rnb[ky][p + kx], acc);
                qr[c][p] = acc;
            }
        }
        // QW4: v-half of q_w repacked float4-aligned, one (c,ky) row per thread
        if (tid < 30) {
            int c = tid / 3, ky = tid % 3;
            float* dst = S + QW4_OFF + c * 12 + ky * 4;
            dst[0] = SW[171 + c * 18 + 9 + ky * 3 + 0];
            dst[1] = SW[171 + c * 18 + 9 + ky * 3 + 1];
            dst[2] = SW[171 + c * 18 + 9 + ky * 3 + 2];
            dst[3] = 0.f;
        }
        // re-zero vA/vB region (was X0/X1 with x data); v0 = 0, rings stay 0 forever
        for (int i = tid; i < 2312; i += 512) ((float4*)S)[i] = z4;
    }
    __syncthreads();

    // phase 4: 50 VI steps, double-buffered v in LDS (ends with result in vA)
    float* vA = S;
    float* vB = S + 4624;
    const float* qw4 = S + QW4_OFF;
#pragma unroll 1
    for (int k = 0; k < K_ITERS / 2; ++k) {
        vi_step(vA, vB, row, col0, qr, qw4);
        __syncthreads();
        vi_step(vB, vA, row, col0, qr, qw4);
        __syncthreads();
    }

    // phase 5: final q at (pos_x, pos_y) + FC, by the owning thread.
    // Recompute the r-part of q from SR (still intact) instead of reading
    // qr[c][p] with runtime p -- a runtime index would force the whole qr
    // array into scratch. Same fmaf order as phase 3 -> bitwise identical.
    int pr = pos_x[b], pc = pos_y[b];
    if (row == pr && (pc >> 3) == (tid & 7)) {
        const float* SR = S + SR_OFF;
        float qf[10];
#pragma unroll
        for (int c = 0; c < 10; ++c) {
            float acc = SW[351 + c];
#pragma unroll
            for (int ky = 0; ky < 3; ++ky)
#pragma unroll
                for (int kx = 0; kx < 3; ++kx)
                    acc = fmaf(SW[171 + c * 18 + ky * 3 + kx], SR[(pr + ky) * 68 + pc + kx], acc);
#pragma unroll
            for (int ky = 0; ky < 3; ++ky)
#pragma unroll
                for (int kx = 0; kx < 3; ++kx)
                    acc = fmaf(SW[171 + c * 18 + 9 + ky * 3 + kx], vA[(pr + ky) * 68 + pc + kx], acc);
            qf[c] = acc;
        }
#pragma unroll
        for (int o = 0; o < 8; ++o) {
            float s = 0.f;
#pragma unroll
            for (int c = 0; c < 10; ++c) s = fmaf(SW[361 + o * 10 + c], qf[c], s);
            out[b * 8 + o] = s;
        }
    }
}

extern "C" void kernel_launch(void* const* d_in, const int* in_sizes, int n_in,
                              void* d_out, int out_size, void* d_ws, size_t ws_size,
                              hipStream_t stream) {
    const float* x     = (const float*)d_in[0];
    const int*   pos_x = (const int*)d_in[1];
    const int*   pos_y = (const int*)d_in[2];
    const float* h_w   = (const float*)d_in[3];
    const float* h_b   = (const float*)d_in[4];
    const float* r_w   = (const float*)d_in[5];
    const float* r_b   = (const float*)d_in[6];
    const float* q_w   = (const float*)d_in[7];
    const float* q_b   = (const float*)d_in[8];
    const float* fc_w  = (const float*)d_in[9];
    float* out = (float*)d_out;

    vin_main<<<128, 512, 0, stream>>>(x, pos_x, pos_y, h_w, h_b, r_w, r_b, q_w, q_b, fc_w, out);
}

// Round 8
// 203.679 us; speedup vs baseline: 1.9208x; 1.9208x over previous
//
#include <hip/hip_runtime.h>

#define K_ITERS 50

typedef float v4f __attribute__((ext_vector_type(4)));

// LDS float layout:
//  [0, 4624)      : setup scratch (h_w 2700 | r_w 1350 | h_b 150) -> X0 (68x68 ring-2) -> vA (66x68 ring-1)
//  [4624, 9248)   : X1 (68x68 ring-2)  -> reused as vB (66x68 ring-1)
//  [9248, 13736)  : R  (66x68 ring-1)  -- intact through phase 5
//  [13736, 14178) : weights: w2(162) rhb(+162) qw(+171,180) qb(+351,10) fcw(+361,80) rb(+441)
//  [14180, 14300) : QWP: v-half of q_w, padded rows: qwp[c*12 + j] = qwv[c][j], j<9 (16B-aligned rows)
#define SR_OFF 9248
#define SW_OFF 13736
#define QWP_OFF 14180
#define LDS_TOT 14300

// VI step. The allocator is hard-capped at 128 VGPRs (VGPR_Count=124 =
// qr80+nb36+vmax8 in every variant; launch-bounds/pins/readfirstlane/global
// routing all failed to move it), and each __syncthreads() clobbers LDS, so
// the 90 loop weights are MANDATORILY reloaded from LDS every step. The
// binding pipe is LDS instruction issue (90 scalar reloads x 8 waves ~= 4200
// cyc/CU/step on top of ~1100 cyc tile traffic > ~3100 cyc VALU floor).
// Only the reload WIDTH is controllable: read each channel's 9 weights as
// v4f+v4f+float (3 LDS instrs, 9 VGPRs -- same register footprint as the
// scalar path) from the 16B-aligned padded QWP copy. NO volatile: round 7
// proved volatile over-constrains scheduling -> qr spilled (44 MB scratch).
__device__ __forceinline__ void vi_step(const float* __restrict__ cur, float* __restrict__ nxt,
                                        int row, int col0,
                                        const float (&qr)[10][8], const float* __restrict__ qwp) {
    float nb[3][12];
#pragma unroll
    for (int dy = 0; dy < 3; ++dy) {
#pragma unroll
        for (int j = 0; j < 3; ++j) {
            float4 v = *(const float4*)&cur[(row + dy) * 68 + col0 + 4 * j];
            nb[dy][4 * j + 0] = v.x; nb[dy][4 * j + 1] = v.y;
            nb[dy][4 * j + 2] = v.z; nb[dy][4 * j + 3] = v.w;
        }
    }
    float vmax[8];
#pragma unroll
    for (int c = 0; c < 10; ++c) {
        const v4f* wq = (const v4f*)(qwp + 12 * c);
        v4f wA = wq[0];                 // taps 0..3
        v4f wB = wq[1];                 // taps 4..7
        float w8 = qwp[12 * c + 8];     // tap 8
#pragma unroll
        for (int p = 0; p < 8; ++p) {
            float acc = qr[c][p];
            // tap order ky*3+kx = 0..8, identical fmaf order -> bitwise identical
            acc = fmaf(wA.x, nb[0][p + 0], acc);
            acc = fmaf(wA.y, nb[0][p + 1], acc);
            acc = fmaf(wA.z, nb[0][p + 2], acc);
            acc = fmaf(wA.w, nb[1][p + 0], acc);
            acc = fmaf(wB.x, nb[1][p + 1], acc);
            acc = fmaf(wB.y, nb[1][p + 2], acc);
            acc = fmaf(wB.z, nb[2][p + 0], acc);
            acc = fmaf(wB.w, nb[2][p + 1], acc);
            acc = fmaf(w8,   nb[2][p + 2], acc);
            vmax[p] = (c == 0) ? acc : fmaxf(vmax[p], acc);
        }
    }
#pragma unroll
    for (int p = 0; p < 8; ++p)
        nxt[(row + 1) * 68 + col0 + 1 + p] = vmax[p];
}

// (512,2): best-measured config (124.6us round 2; (512,1) -> ~160us).
// qr indexed ONLY with compile-time constants (a runtime index demotes the
// whole array to scratch: that was the 20.5 MB WRITE_SIZE regression).
__launch_bounds__(512, 2)
__global__ void vin_main(const float* __restrict__ x,
                         const int* __restrict__ pos_x, const int* __restrict__ pos_y,
                         const float* __restrict__ h_w, const float* __restrict__ h_b,
                         const float* __restrict__ r_w, const float* __restrict__ r_b,
                         const float* __restrict__ q_w, const float* __restrict__ q_b,
                         const float* __restrict__ fc_w, float* __restrict__ out) {
    __shared__ __align__(16) float S[LDS_TOT];
    const int tid = threadIdx.x;
    const int b = blockIdx.x;
    const int row = tid >> 3;          // 0..63
    const int col0 = (tid & 7) << 3;   // 0,8,..,56
    float* SW = S + SW_OFF;

    // phase A: stage raw weights into scratch (region later zeroed for X0/X1),
    //          and loop weights into SW[171..442)
    for (int i = tid; i < 2700; i += 512) S[i] = h_w[i];
    for (int i = tid; i < 1350; i += 512) S[2700 + i] = r_w[i];
    if (tid < 150) S[4050 + tid] = h_b[tid];
    for (int i = tid; i < 180; i += 512) SW[171 + i] = q_w[i];
    if (tid < 10) SW[351 + tid] = q_b[tid];
    for (int i = tid; i < 80; i += 512) SW[361 + i] = fc_w[i];
    if (tid == 0) SW[441] = r_b[0];
    __syncthreads();

    // phase B: composite 2-stage conv weights w2[2][9][9] + rhb[9] (fmaf order
    // identical to the original vin_setup kernel -> bitwise-identical results)
    if (tid < 162) {
        int i = tid / 81, rem = tid % 81, dq = rem / 9, ds = rem % 9;
        const float* rw = S + 2700;
        float s = 0.f;
        for (int m = 0; m < 150; ++m)
            s = fmaf(rw[m * 9 + dq], S[(m * 2 + i) * 9 + ds], s);
        SW[tid] = s;
    } else if (tid < 171) {
        int dq = tid - 162;
        const float* rw = S + 2700;
        const float* hb = S + 4050;
        float s = 0.f;
        for (int m = 0; m < 150; ++m)
            s = fmaf(rw[m * 9 + dq], hb[m], s);
        SW[tid] = s;
    }
    __syncthreads();

    // phase 0: zero X0/X1/R regions (13736 = 4*3434 floats)
    float4 z4 = make_float4(0.f, 0.f, 0.f, 0.f);
    for (int i = tid; i < 3434; i += 512) ((float4*)S)[i] = z4;
    __syncthreads();

    // phase 1: stage x[b] into X0/X1 interior (ring-2 stays zero)
    {
        const float4* xg = (const float4*)(x + (size_t)b * 8192);
        for (int i = tid; i < 2048; i += 512) {
            float4 v = xg[i];
            int ch = i >> 10, rem = i & 1023;
            int y = rem >> 4, xc = (rem & 15) << 2;
            float* dst = S + ch * 4624 + (y + 2) * 68 + xc + 2;
            dst[0] = v.x; dst[1] = v.y; dst[2] = v.z; dst[3] = v.w;
        }
    }
    __syncthreads();

    // phase 2: r = composite 2-stage conv via w2/rhb, exact border clipping on q
    {
        float xb0[5][12], xb1[5][12];
        const float* X0 = S;
        const float* X1 = S + 4624;
#pragma unroll
        for (int dy = 0; dy < 5; ++dy) {
#pragma unroll
            for (int j = 0; j < 3; ++j) {
                float4 a = *(const float4*)&X0[(row + dy) * 68 + col0 + 4 * j];
                xb0[dy][4 * j + 0] = a.x; xb0[dy][4 * j + 1] = a.y;
                xb0[dy][4 * j + 2] = a.z; xb0[dy][4 * j + 3] = a.w;
                float4 c = *(const float4*)&X1[(row + dy) * 68 + col0 + 4 * j];
                xb1[dy][4 * j + 0] = c.x; xb1[dy][4 * j + 1] = c.y;
                xb1[dy][4 * j + 2] = c.z; xb1[dy][4 * j + 3] = c.w;
            }
        }
        float racc[8];
        float rbv = SW[441];
#pragma unroll
        for (int p = 0; p < 8; ++p) racc[p] = rbv;
#pragma unroll
        for (int dqy = 0; dqy < 3; ++dqy) {
            bool rowok = (row + dqy >= 1) && (row + dqy <= 64);
#pragma unroll
            for (int dqx = 0; dqx < 3; ++dqx) {
                int dq = dqy * 3 + dqx;
                float rh = SW[162 + dq];
                float w20[9], w21[9];
#pragma unroll
                for (int ds = 0; ds < 9; ++ds) {
                    w20[ds] = SW[dq * 9 + ds];
                    w21[ds] = SW[81 + dq * 9 + ds];
                }
#pragma unroll
                for (int p = 0; p < 8; ++p) {
                    float t = rh;
#pragma unroll
                    for (int dsy = 0; dsy < 3; ++dsy)
#pragma unroll
                        for (int dsx = 0; dsx < 3; ++dsx) {
                            int ds = dsy * 3 + dsx;
                            t = fmaf(w20[ds], xb0[dqy + dsy][p + dqx + dsx], t);
                            t = fmaf(w21[ds], xb1[dqy + dsy][p + dqx + dsx], t);
                        }
                    int qx = col0 + p + dqx - 1;
                    bool ok = rowok && (qx >= 0) && (qx < 64);
                    racc[p] += ok ? t : 0.f;
                }
            }
        }
        float* SR = S + SR_OFF;
#pragma unroll
        for (int p = 0; p < 8; ++p)
            SR[(row + 1) * 68 + col0 + 1 + p] = racc[p];
    }
    __syncthreads();

    // phase 3: qr = conv(r, q_w[:,0]) + q_b into registers; build QWP; re-zero v buffers
    float qr[10][8];
    {
        float rnb[3][12];
        const float* SR = S + SR_OFF;
#pragma unroll
        for (int dy = 0; dy < 3; ++dy) {
#pragma unroll
            for (int j = 0; j < 3; ++j) {
                float4 v = *(const float4*)&SR[(row + dy) * 68 + col0 + 4 * j];
                rnb[dy][4 * j + 0] = v.x; rnb[dy][4 * j + 1] = v.y;
                rnb[dy][4 * j + 2] = v.z; rnb[dy][4 * j + 3] = v.w;
            }
        }
#pragma unroll
        for (int c = 0; c < 10; ++c) {
            float qbc = SW[351 + c];
            float w[9];
#pragma unroll
            for (int j = 0; j < 9; ++j) w[j] = SW[171 + c * 18 + j];
#pragma unroll
            for (int p = 0; p < 8; ++p) {
                float acc = qbc;
#pragma unroll
                for (int ky = 0; ky < 3; ++ky)
#pragma unroll
                    for (int kx = 0; kx < 3; ++kx)
                        acc = fmaf(w[ky * 3 + kx], rnb[ky][p + kx], acc);
                qr[c][p] = acc;
            }
        }
        // QWP: v-half of q_w repacked to 16B-aligned 12-float rows
        if (tid < 90) {
            int c = tid / 9, j = tid % 9;
            S[QWP_OFF + c * 12 + j] = SW[171 + c * 18 + 9 + j];
        }
        // re-zero vA/vB region (was X0/X1 with x data); v0 = 0, rings stay 0 forever
        for (int i = tid; i < 2312; i += 512) ((float4*)S)[i] = z4;
    }
    __syncthreads();

    // phase 4: 50 VI steps, double-buffered v in LDS (ends with result in vA)
    float* vA = S;
    float* vB = S + 4624;
    const float* qwp = S + QWP_OFF;
#pragma unroll 1
    for (int k = 0; k < K_ITERS / 2; ++k) {
        vi_step(vA, vB, row, col0, qr, qwp);
        __syncthreads();
        vi_step(vB, vA, row, col0, qr, qwp);
        __syncthreads();
    }

    // phase 5: final q at (pos_x, pos_y) + FC, by the owning thread.
    // Recompute the r-part of q from SR (still intact) instead of reading
    // qr[c][p] with runtime p -- a runtime index would force the whole qr
    // array into scratch. Same fmaf order as phase 3 -> bitwise identical.
    int pr = pos_x[b], pc = pos_y[b];
    if (row == pr && (pc >> 3) == (tid & 7)) {
        const float* SR = S + SR_OFF;
        float qf[10];
#pragma unroll
        for (int c = 0; c < 10; ++c) {
            float acc = SW[351 + c];
#pragma unroll
            for (int ky = 0; ky < 3; ++ky)
#pragma unroll
                for (int kx = 0; kx < 3; ++kx)
                    acc = fmaf(SW[171 + c * 18 + ky * 3 + kx], SR[(pr + ky) * 68 + pc + kx], acc);
#pragma unroll
            for (int ky = 0; ky < 3; ++ky)
#pragma unroll
                for (int kx = 0; kx < 3; ++kx)
                    acc = fmaf(SW[171 + c * 18 + 9 + ky * 3 + kx], vA[(pr + ky) * 68 + pc + kx], acc);
            qf[c] = acc;
        }
#pragma unroll
        for (int o = 0; o < 8; ++o) {
            float s = 0.f;
#pragma unroll
            for (int c = 0; c < 10; ++c) s = fmaf(SW[361 + o * 10 + c], qf[c], s);
            out[b * 8 + o] = s;
        }
    }
}

extern "C" void kernel_launch(void* const* d_in, const int* in_sizes, int n_in,
                              void* d_out, int out_size, void* d_ws, size_t ws_size,
                              hipStream_t stream) {
    const float* x     = (const float*)d_in[0];
    const int*   pos_x = (const int*)d_in[1];
    const int*   pos_y = (const int*)d_in[2];
    const float* h_w   = (const float*)d_in[3];
    const float* h_b   = (const float*)d_in[4];
    const float* r_w   = (const float*)d_in[5];
    const float* r_b   = (const float*)d_in[6];
    const float* q_w   = (const float*)d_in[7];
    const float* q_b   = (const float*)d_in[8];
    const float* fc_w  = (const float*)d_in[9];
    float* out = (float*)d_out;

    vin_main<<<128, 512, 0, stream>>>(x, pos_x, pos_y, h_w, h_b, r_w, r_b, q_w, q_b, fc_w, out);
}

// Round 9
// 188.687 us; speedup vs baseline: 2.0734x; 1.0795x over previous
//
#include <hip/hip_runtime.h>

#define K_ITERS 50

// LDS float layout (total 14178 floats = 56712 B):
//  [0, 4624)      : setup scratch (h_w 2700 | r_w 1350 | h_b 150) -> X0 (68x68 ring-2) -> vA (66x68 ring-1)
//  [4624, 9248)   : X1 (68x68 ring-2)  -> reused as vB (66x68 ring-1)
//  [9248, 13736)  : R  (66x68 ring-1)  -- intact through phase 5
//  [13736, 14178) : weights: w2(162) rhb(+162) qw(+171,180) qb(+351,10) fcw(+361,80) rb(+441)
#define SR_OFF 9248
#define SW_OFF 13736
#define LDS_TOT 14178

__device__ __forceinline__ void vi_step(const float* __restrict__ cur, float* __restrict__ nxt,
                                        int row, int col0,
                                        const float (&qr)[10][8], const float (&qwv)[10][9]) {
    float nb[3][12];
#pragma unroll
    for (int dy = 0; dy < 3; ++dy) {
#pragma unroll
        for (int j = 0; j < 3; ++j) {
            float4 v = *(const float4*)&cur[(row + dy) * 68 + col0 + 4 * j];
            nb[dy][4 * j + 0] = v.x; nb[dy][4 * j + 1] = v.y;
            nb[dy][4 * j + 2] = v.z; nb[dy][4 * j + 3] = v.w;
        }
    }
    float vmax[8];
#pragma unroll
    for (int p = 0; p < 8; ++p) {
        float a[10];
#pragma unroll
        for (int c = 0; c < 10; ++c) {
            float acc = qr[c][p];
#pragma unroll
            for (int ky = 0; ky < 3; ++ky)
#pragma unroll
                for (int kx = 0; kx < 3; ++kx)
                    acc = fmaf(qwv[c][ky * 3 + kx], nb[ky][p + kx], acc);
            a[c] = acc;
        }
        // triple-nested fmaxf -> v_max3_f32 fusable; order-invariant -> bitwise identical
        float m = fmaxf(fmaxf(a[0], a[1]), a[2]);
        m = fmaxf(fmaxf(m, a[3]), a[4]);
        m = fmaxf(fmaxf(m, a[5]), a[6]);
        m = fmaxf(fmaxf(m, a[7]), a[8]);
        vmax[p] = fmaxf(m, a[9]);
    }
#pragma unroll
    for (int p = 0; p < 8; ++p)
        nxt[(row + 1) * 68 + col0 + 1 + p] = vmax[p];
}

// amdgpu_waves_per_eu(2,2): the DIRECT backend attribute for the occupancy
// target. HW allows 256 VGPR/wave at 2 waves/SIMD (our actual occupancy:
// 8-wave block, 1 block/CU, grid 128 < 256 CUs). __launch_bounds__ 2nd arg
// never moved the allocator off its 128-reg (4 waves/EU) target: VGPR_Count
// pinned at 124 = qr80+nb36+vmax8 in rounds 2-8, leaving qwv[90] remat'd
// from LDS every step -- 720 ds_read_b32/CU/step ~= 4200 cyc on the LDS pipe
// (per-wave bill 9xb128 + 90xb32 + 8 writes ~= 676 cyc x 8 waves ~= 5400 =
// measured 5440 cyc/step). With a real 256-reg budget, qr+qwv+nb+vmax ~= 214
// fits, LDS drops to ~136 instrs/CU/step and the loop becomes VALU-bound.
// qr/qwv indexed ONLY with compile-time constants (runtime index = scratch).
__attribute__((amdgpu_flat_work_group_size(512, 512), amdgpu_waves_per_eu(2, 2)))
__global__ void vin_main(const float* __restrict__ x,
                         const int* __restrict__ pos_x, const int* __restrict__ pos_y,
                         const float* __restrict__ h_w, const float* __restrict__ h_b,
                         const float* __restrict__ r_w, const float* __restrict__ r_b,
                         const float* __restrict__ q_w, const float* __restrict__ q_b,
                         const float* __restrict__ fc_w, float* __restrict__ out) {
    __shared__ __align__(16) float S[LDS_TOT];
    const int tid = threadIdx.x;
    const int b = blockIdx.x;
    const int row = tid >> 3;          // 0..63
    const int col0 = (tid & 7) << 3;   // 0,8,..,56
    float* SW = S + SW_OFF;

    // phase A: stage raw weights into scratch (region later zeroed for X0/X1),
    //          and loop weights into SW[171..442)
    for (int i = tid; i < 2700; i += 512) S[i] = h_w[i];
    for (int i = tid; i < 1350; i += 512) S[2700 + i] = r_w[i];
    if (tid < 150) S[4050 + tid] = h_b[tid];
    for (int i = tid; i < 180; i += 512) SW[171 + i] = q_w[i];
    if (tid < 10) SW[351 + tid] = q_b[tid];
    for (int i = tid; i < 80; i += 512) SW[361 + i] = fc_w[i];
    if (tid == 0) SW[441] = r_b[0];
    __syncthreads();

    // phase B: composite 2-stage conv weights w2[2][9][9] + rhb[9] (fmaf order
    // identical to the original vin_setup kernel -> bitwise-identical results)
    if (tid < 162) {
        int i = tid / 81, rem = tid % 81, dq = rem / 9, ds = rem % 9;
        const float* rw = S + 2700;
        float s = 0.f;
        for (int m = 0; m < 150; ++m)
            s = fmaf(rw[m * 9 + dq], S[(m * 2 + i) * 9 + ds], s);
        SW[tid] = s;
    } else if (tid < 171) {
        int dq = tid - 162;
        const float* rw = S + 2700;
        const float* hb = S + 4050;
        float s = 0.f;
        for (int m = 0; m < 150; ++m)
            s = fmaf(rw[m * 9 + dq], hb[m], s);
        SW[tid] = s;
    }
    __syncthreads();

    // phase 0: zero X0/X1/R regions (13736 = 4*3434 floats)
    float4 z4 = make_float4(0.f, 0.f, 0.f, 0.f);
    for (int i = tid; i < 3434; i += 512) ((float4*)S)[i] = z4;
    __syncthreads();

    // phase 1: stage x[b] into X0/X1 interior (ring-2 stays zero)
    {
        const float4* xg = (const float4*)(x + (size_t)b * 8192);
        for (int i = tid; i < 2048; i += 512) {
            float4 v = xg[i];
            int ch = i >> 10, rem = i & 1023;
            int y = rem >> 4, xc = (rem & 15) << 2;
            float* dst = S + ch * 4624 + (y + 2) * 68 + xc + 2;
            dst[0] = v.x; dst[1] = v.y; dst[2] = v.z; dst[3] = v.w;
        }
    }
    __syncthreads();

    // phase 2: r = composite 2-stage conv via w2/rhb, exact border clipping on q
    {
        float xb0[5][12], xb1[5][12];
        const float* X0 = S;
        const float* X1 = S + 4624;
#pragma unroll
        for (int dy = 0; dy < 5; ++dy) {
#pragma unroll
            for (int j = 0; j < 3; ++j) {
                float4 a = *(const float4*)&X0[(row + dy) * 68 + col0 + 4 * j];
                xb0[dy][4 * j + 0] = a.x; xb0[dy][4 * j + 1] = a.y;
                xb0[dy][4 * j + 2] = a.z; xb0[dy][4 * j + 3] = a.w;
                float4 c = *(const float4*)&X1[(row + dy) * 68 + col0 + 4 * j];
                xb1[dy][4 * j + 0] = c.x; xb1[dy][4 * j + 1] = c.y;
                xb1[dy][4 * j + 2] = c.z; xb1[dy][4 * j + 3] = c.w;
            }
        }
        float racc[8];
        float rbv = SW[441];
#pragma unroll
        for (int p = 0; p < 8; ++p) racc[p] = rbv;
#pragma unroll
        for (int dqy = 0; dqy < 3; ++dqy) {
            bool rowok = (row + dqy >= 1) && (row + dqy <= 64);
#pragma unroll
            for (int dqx = 0; dqx < 3; ++dqx) {
                int dq = dqy * 3 + dqx;
                float rh = SW[162 + dq];
                float w20[9], w21[9];
#pragma unroll
                for (int ds = 0; ds < 9; ++ds) {
                    w20[ds] = SW[dq * 9 + ds];
                    w21[ds] = SW[81 + dq * 9 + ds];
                }
#pragma unroll
                for (int p = 0; p < 8; ++p) {
                    float t = rh;
#pragma unroll
                    for (int dsy = 0; dsy < 3; ++dsy)
#pragma unroll
                        for (int dsx = 0; dsx < 3; ++dsx) {
                            int ds = dsy * 3 + dsx;
                            t = fmaf(w20[ds], xb0[dqy + dsy][p + dqx + dsx], t);
                            t = fmaf(w21[ds], xb1[dqy + dsy][p + dqx + dsx], t);
                        }
                    int qx = col0 + p + dqx - 1;
                    bool ok = rowok && (qx >= 0) && (qx < 64);
                    racc[p] += ok ? t : 0.f;
                }
            }
        }
        float* SR = S + SR_OFF;
#pragma unroll
        for (int p = 0; p < 8; ++p)
            SR[(row + 1) * 68 + col0 + 1 + p] = racc[p];
    }
    __syncthreads();

    // phase 3: qr = conv(r, q_w[:,0]) + q_b into registers; loop weights pinned
    //          into VGPRs; re-zero v buffers
    float qr[10][8];
    float qwv[10][9];
    {
        float rnb[3][12];
        const float* SR = S + SR_OFF;
#pragma unroll
        for (int dy = 0; dy < 3; ++dy) {
#pragma unroll
            for (int j = 0; j < 3; ++j) {
                float4 v = *(const float4*)&SR[(row + dy) * 68 + col0 + 4 * j];
                rnb[dy][4 * j + 0] = v.x; rnb[dy][4 * j + 1] = v.y;
                rnb[dy][4 * j + 2] = v.z; rnb[dy][4 * j + 3] = v.w;
            }
        }
#pragma unroll
        for (int c = 0; c < 10; ++c) {
            float qbc = SW[351 + c];
            float w[9];
#pragma unroll
            for (int j = 0; j < 9; ++j) w[j] = SW[171 + c * 18 + j];
#pragma unroll
            for (int p = 0; p < 8; ++p) {
                float acc = qbc;
#pragma unroll
                for (int ky = 0; ky < 3; ++ky)
#pragma unroll
                    for (int kx = 0; kx < 3; ++kx)
                        acc = fmaf(w[ky * 3 + kx], rnb[ky][p + kx], acc);
                qr[c][p] = acc;
            }
        }
        // loop weights -> VGPRs, PINNED (opaque to remat). With the 256-reg
        // budget from amdgpu_waves_per_eu(2,2) these now stay resident.
#pragma unroll
        for (int c = 0; c < 10; ++c)
#pragma unroll
            for (int j = 0; j < 9; ++j) {
                qwv[c][j] = SW[171 + c * 18 + 9 + j];
                asm volatile("" : "+v"(qwv[c][j]));
            }
        // re-zero vA/vB region (was X0/X1 with x data); v0 = 0, rings stay 0 forever
        for (int i = tid; i < 2312; i += 512) ((float4*)S)[i] = z4;
    }
    __syncthreads();

    // phase 4: 50 VI steps, double-buffered v in LDS (ends with result in vA)
    float* vA = S;
    float* vB = S + 4624;
#pragma unroll 1
    for (int k = 0; k < K_ITERS / 2; ++k) {
        vi_step(vA, vB, row, col0, qr, qwv);
        __syncthreads();
        vi_step(vB, vA, row, col0, qr, qwv);
        __syncthreads();
    }

    // phase 5: final q at (pos_x, pos_y) + FC, by the owning thread.
    // Recompute the r-part of q from SR (still intact) instead of reading
    // qr[c][p] with runtime p -- a runtime index would force the whole qr
    // array into scratch. Same fmaf order as phase 3 -> bitwise identical.
    int pr = pos_x[b], pc = pos_y[b];
    if (row == pr && (pc >> 3) == (tid & 7)) {
        const float* SR = S + SR_OFF;
        float qf[10];
#pragma unroll
        for (int c = 0; c < 10; ++c) {
            float acc = SW[351 + c];
#pragma unroll
            for (int ky = 0; ky < 3; ++ky)
#pragma unroll
                for (int kx = 0; kx < 3; ++kx)
                    acc = fmaf(SW[171 + c * 18 + ky * 3 + kx], SR[(pr + ky) * 68 + pc + kx], acc);
#pragma unroll
            for (int ky = 0; ky < 3; ++ky)
#pragma unroll
                for (int kx = 0; kx < 3; ++kx)
                    acc = fmaf(SW[171 + c * 18 + 9 + ky * 3 + kx], vA[(pr + ky) * 68 + pc + kx], acc);
            qf[c] = acc;
        }
#pragma unroll
        for (int o = 0; o < 8; ++o) {
            float s = 0.f;
#pragma unroll
            for (int c = 0; c < 10; ++c) s = fmaf(SW[361 + o * 10 + c], qf[c], s);
            out[b * 8 + o] = s;
        }
    }
}

extern "C" void kernel_launch(void* const* d_in, const int* in_sizes, int n_in,
                              void* d_out, int out_size, void* d_ws, size_t ws_size,
                              hipStream_t stream) {
    const float* x     = (const float*)d_in[0];
    const int*   pos_x = (const int*)d_in[1];
    const int*   pos_y = (const int*)d_in[2];
    const float* h_w   = (const float*)d_in[3];
    const float* h_b   = (const float*)d_in[4];
    const float* r_w   = (const float*)d_in[5];
    const float* r_b   = (const float*)d_in[6];
    const float* q_w   = (const float*)d_in[7];
    const float* q_b   = (const float*)d_in[8];
    const float* fc_w  = (const float*)d_in[9];
    float* out = (float*)d_out;

    vin_main<<<128, 512, 0, stream>>>(x, pos_x, pos_y, h_w, h_b, r_w, r_b, q_w, q_b, fc_w, out);
}